// Round 5
// baseline (157.346 us; speedup 1.0000x reference)
//
#include <hip/hip_runtime.h>
#include <math.h>

typedef __bf16 bf16;
typedef bf16 bf16x2 __attribute__((ext_vector_type(2)));
typedef bf16 bf16x4 __attribute__((ext_vector_type(4)));
typedef bf16 bf16x8 __attribute__((ext_vector_type(8)));
typedef float f32x4 __attribute__((ext_vector_type(4)));

constexpr int CENTER = 31;

static __device__ __forceinline__ unsigned short f2bf_bits(float f) {
    bf16 b = (bf16)f;
    return __builtin_bit_cast(unsigned short, b);
}

// =====================================================================
// Kernel 1: Q/K projection GEMM via MFMA (bf16 in, bf16 out).
// Side-emits hidden^T in MFMA-tile-packed layout:
//   htp[b][kc][half][dt][l15][e]  (e = quad*8+j, 32 keys per half)
// so the attention PV A-fragment is a contiguous 1KB coalesced load.
// grid = (64 pos-tiles x 4 out-tiles x {q,k}), block 256.
// =====================================================================
__global__ __launch_bounds__(256)
void qkproj_kernel(const float* __restrict__ hid,
                   const float* __restrict__ Wq, const float* __restrict__ bq,
                   const float* __restrict__ Wk, const float* __restrict__ bk,
                   bf16* __restrict__ qb, bf16* __restrict__ kb,
                   bf16* __restrict__ htp)
{
    __shared__ __attribute__((aligned(16))) bf16 As[128][72];
    __shared__ __attribute__((aligned(16))) bf16 Bs[128][72];

    const int t  = threadIdx.x;
    const int pt = blockIdx.x;
    const int ot = blockIdx.y;
    const int z  = blockIdx.z;
    const float* W    = z ? Wk : Wq;
    const float* bias = z ? bk : bq;
    bf16* outp        = z ? kb : qb;
    const float scale = z ? 1.0f : 0.125f;
    const int p0 = pt * 128;
    const int b  = p0 >> 10;

    {
        int row = t >> 1, ch = (t & 1) * 32;
        const float4* asrc = (const float4*)(hid + (size_t)(p0 + row) * 64 + ch);
        const float4* bsrc = (const float4*)(W + (size_t)(ot * 128 + row) * 64 + ch);
        bf16 ta[32], tb[32];
        #pragma unroll
        for (int u = 0; u < 8; ++u) {
            float4 va = asrc[u], vb = bsrc[u];
            ta[4*u+0] = (bf16)va.x; ta[4*u+1] = (bf16)va.y;
            ta[4*u+2] = (bf16)va.z; ta[4*u+3] = (bf16)va.w;
            tb[4*u+0] = (bf16)vb.x; tb[4*u+1] = (bf16)vb.y;
            tb[4*u+2] = (bf16)vb.z; tb[4*u+3] = (bf16)vb.w;
        }
        #pragma unroll
        for (int u = 0; u < 4; ++u) {
            *(int4*)&As[row][ch + u * 8] = ((int4*)ta)[u];
            *(int4*)&Bs[row][ch + u * 8] = ((int4*)tb)[u];
        }
    }
    __syncthreads();

    // side-emit hidden^T, tile-packed (once: ot==0, z==0 blocks)
    if (ot == 0 && z == 0) {
        int d = t >> 2, ps = (t & 3) * 32;
        int pp = (p0 & 1023) + ps;
        int kc = pp >> 6, half = (pp >> 5) & 1;
        bf16* hdst = htp + (size_t)b * 65536 + kc * 4096 + half * 2048
                         + (d >> 4) * 512 + (d & 15) * 32;
        #pragma unroll
        for (int ii = 0; ii < 32; ii += 4) {
            ushort4 pk;
            pk.x = __builtin_bit_cast(unsigned short, As[ps + ii + 0][d]);
            pk.y = __builtin_bit_cast(unsigned short, As[ps + ii + 1][d]);
            pk.z = __builtin_bit_cast(unsigned short, As[ps + ii + 2][d]);
            pk.w = __builtin_bit_cast(unsigned short, As[ps + ii + 3][d]);
            *(ushort4*)(hdst + ii) = pk;
        }
    }

    const int w = t >> 6, ln = t & 63, l15 = ln & 15, quad = ln >> 4;

    bf16x8 a[2][2];
    #pragma unroll
    for (int mt = 0; mt < 2; ++mt) {
        a[mt][0] = *(const bf16x8*)&As[w * 32 + mt * 16 + l15][quad * 8];
        a[mt][1] = *(const bf16x8*)&As[w * 32 + mt * 16 + l15][32 + quad * 8];
    }

    const f32x4 z4 = {0.f, 0.f, 0.f, 0.f};
    f32x4 acc[2][8];
    #pragma unroll
    for (int mt = 0; mt < 2; ++mt)
        #pragma unroll
        for (int nt = 0; nt < 8; ++nt) acc[mt][nt] = z4;

    #pragma unroll
    for (int nt = 0; nt < 8; ++nt) {
        bf16x8 b0 = *(const bf16x8*)&Bs[nt * 16 + l15][quad * 8];
        bf16x8 b1 = *(const bf16x8*)&Bs[nt * 16 + l15][32 + quad * 8];
        #pragma unroll
        for (int mt = 0; mt < 2; ++mt) {
            acc[mt][nt] = __builtin_amdgcn_mfma_f32_16x16x32_bf16(a[mt][0], b0, acc[mt][nt], 0, 0, 0);
            acc[mt][nt] = __builtin_amdgcn_mfma_f32_16x16x32_bf16(a[mt][1], b1, acc[mt][nt], 0, 0, 0);
        }
    }

    #pragma unroll
    for (int nt = 0; nt < 8; ++nt) {
        int o = ot * 128 + nt * 16 + l15;
        float bv = bias[o];
        int hh = o >> 6, d = o & 63;
        #pragma unroll
        for (int mt = 0; mt < 2; ++mt)
            #pragma unroll
            for (int r = 0; r < 4; ++r) {
                int pos = (p0 & 1023) + w * 32 + mt * 16 + quad * 4 + r;
                float val = (acc[mt][nt][r] + bv) * scale;
                outp[(((size_t)b * 8 + hh) * 1024 + pos) * 64 + d] = (bf16)val;
            }
    }
}

// =====================================================================
// Kernel 2: positional-bias precompute via MFMA (unchanged).
// =====================================================================
__global__ __launch_bounds__(256)
void bias_kernel(const bf16* __restrict__ qb,
                 const float* __restrict__ row_emb, const float* __restrict__ col_emb,
                 bf16* __restrict__ rowbias, bf16* __restrict__ colbias)
{
    __shared__ __attribute__((aligned(16))) bf16 embRs[63][40];
    __shared__ __attribute__((aligned(16))) bf16 embCs[63][40];

    const int t  = threadIdx.x;
    const int bh = blockIdx.x;
    const int sg = blockIdx.y;

    for (int i = t; i < 2016; i += 256) embRs[i >> 5][i & 31] = (bf16)row_emb[i];
    for (int i = t; i < 2016; i += 256) embCs[i >> 5][i & 31] = (bf16)col_emb[i];
    __syncthreads();

    const int w = t >> 6, ln = t & 63, l15 = ln & 15, quad = ln >> 4;

    #pragma unroll
    for (int u = 0; u < 4; ++u) {
        int s = sg * 16 + u * 4 + w;
        bool cm = s >= 32;
        int ij = cm ? s - 32 : s;

        bf16x8 a[2];
        #pragma unroll
        for (int mt = 0; mt < 2; ++mt) {
            const bf16* ap = cm
                ? qb + ((size_t)bh * 1024 + (mt * 16 + l15) * 32 + ij) * 64 + 32 + quad * 8
                : qb + ((size_t)bh * 1024 + ij * 32 + mt * 16 + l15) * 64 + quad * 8;
            a[mt] = *(const bf16x8*)ap;
        }
        bf16* ob = cm ? colbias : rowbias;

        #pragma unroll
        for (int nt = 0; nt < 2; ++nt) {
            int erow = nt * 16 + l15 + CENTER - ij;
            bf16x8 bfrag = cm ? *(const bf16x8*)&embCs[erow][quad * 8]
                              : *(const bf16x8*)&embRs[erow][quad * 8];
            #pragma unroll
            for (int mt = 0; mt < 2; ++mt) {
                f32x4 c = {0.f, 0.f, 0.f, 0.f};
                c = __builtin_amdgcn_mfma_f32_16x16x32_bf16(a[mt], bfrag, c, 0, 0, 0);
                #pragma unroll
                for (int r = 0; r < 4; ++r) {
                    int ql = mt * 16 + quad * 4 + r;
                    int qrow = cm ? ql * 32 + ij : ij * 32 + ql;
                    ob[((size_t)bh * 1024 + qrow) * 32 + nt * 16 + l15] = (bf16)c[r];
                }
            }
        }
    }
}

// =====================================================================
// Kernel 3: MFMA flash attention — BARRIER-FREE loop.
//   K A-frags: contiguous 1KB coalesced global loads (L2-hot).
//   H A-frags: contiguous 1KB loads from tile-packed htp (L2-hot).
//   P: wave-private LDS round-trip (no barriers anywhere in the loop).
// grid (8 q-tiles of 128, 64 bh), block 256 (4 waves x 32 q).
// =====================================================================
__global__ __launch_bounds__(256, 3)
void attn_kernel(const bf16* __restrict__ qb, const bf16* __restrict__ kb,
                 const bf16* __restrict__ htp,
                 const bf16* __restrict__ rowbias, const bf16* __restrict__ colbias,
                 bf16* __restrict__ mixedb)
{
    __shared__ __attribute__((aligned(16))) bf16 Pp[4][32][72];

    const int t  = threadIdx.x;
    const int qt = blockIdx.x;
    const int bh = blockIdx.y;
    const int b  = bh >> 3, h = bh & 7;
    const int q0 = qt * 128;
    const int w = t >> 6, ln = t & 63, l15 = ln & 15, quad = ln >> 4;

    // ---- loop-invariant register preloads ----
    bf16x8 bq_[2][2];           // Q as B-operand (lane = q, k = d)
    float  cbv[2][2][4];        // col bias [mt][key&16][r]
    const bf16* rbp[2];
    #pragma unroll
    for (int mt = 0; mt < 2; ++mt) {
        int qrow = q0 + w * 32 + mt * 16 + l15;
        const bf16* qp = qb + ((size_t)bh * 1024 + qrow) * 64;
        bq_[mt][0] = *(const bf16x8*)(qp + quad * 8);
        bq_[mt][1] = *(const bf16x8*)(qp + 32 + quad * 8);
        #pragma unroll
        for (int par = 0; par < 2; ++par) {
            bf16x4 cv = *(const bf16x4*)(colbias + ((size_t)bh * 1024 + qrow) * 32 + par * 16 + quad * 4);
            #pragma unroll
            for (int r = 0; r < 4; ++r) cbv[mt][par][r] = (float)cv[r];
        }
        rbp[mt] = rowbias + ((size_t)bh * 1024 + qrow) * 32;
    }

    const f32x4 z4 = {0.f, 0.f, 0.f, 0.f};
    f32x4 oacc[2][4];
    float lsum[2] = {0.f, 0.f};
    #pragma unroll
    for (int mt = 0; mt < 2; ++mt)
        #pragma unroll
        for (int dt = 0; dt < 4; ++dt) oacc[mt][dt] = z4;

    bf16* Pw = &Pp[w][0][0];
    const bf16* kfrag = kb + (size_t)bh * 65536 + (size_t)l15 * 64 + quad * 8;
    const bf16* hfrag = htp + (size_t)b * 65536 + (size_t)l15 * 32 + quad * 8;

    for (int kc = 0; kc < 16; ++kc) {
        // ---- S^T = K·Q^T: A = K rows direct from global ----
        f32x4 sf[2][4];
        #pragma unroll
        for (int mt = 0; mt < 2; ++mt)
            #pragma unroll
            for (int kt = 0; kt < 4; ++kt) sf[mt][kt] = z4;
        #pragma unroll
        for (int kt = 0; kt < 4; ++kt) {
            const bf16* kp = kfrag + (size_t)(kc * 64 + kt * 16) * 64;
            bf16x8 aK0 = *(const bf16x8*)kp;
            bf16x8 aK1 = *(const bf16x8*)(kp + 32);
            #pragma unroll
            for (int mt = 0; mt < 2; ++mt) {
                sf[mt][kt] = __builtin_amdgcn_mfma_f32_16x16x32_bf16(aK0, bq_[mt][0], sf[mt][kt], 0, 0, 0);
                sf[mt][kt] = __builtin_amdgcn_mfma_f32_16x16x32_bf16(aK1, bq_[mt][1], sf[mt][kt], 0, 0, 0);
            }
        }

        // row-bias for this chunk (2 key-rows)
        float rb[2][2];
        #pragma unroll
        for (int mt = 0; mt < 2; ++mt) {
            bf16x2 rv = *(const bf16x2*)(rbp[mt] + kc * 2);
            rb[mt][0] = (float)rv[0]; rb[mt][1] = (float)rv[1];
        }

        // ---- bias + exp + row-sum + packed P write (wave-private) ----
        #pragma unroll
        for (int mt = 0; mt < 2; ++mt)
            #pragma unroll
            for (int kt = 0; kt < 4; ++kt) {
                float rbv = rb[mt][kt >> 1];
                ushort4 pk;
                float p0 = __expf(sf[mt][kt][0] + rbv + cbv[mt][kt & 1][0]);
                float p1 = __expf(sf[mt][kt][1] + rbv + cbv[mt][kt & 1][1]);
                float p2 = __expf(sf[mt][kt][2] + rbv + cbv[mt][kt & 1][2]);
                float p3 = __expf(sf[mt][kt][3] + rbv + cbv[mt][kt & 1][3]);
                lsum[mt] += (p0 + p1) + (p2 + p3);
                pk.x = f2bf_bits(p0); pk.y = f2bf_bits(p1);
                pk.z = f2bf_bits(p2); pk.w = f2bf_bits(p3);
                *(ushort4*)&Pw[(mt * 16 + l15) * 72 + kt * 16 + quad * 4] = pk;
            }

        // ---- O^T += H^T·P^T: A = packed htp direct from global ----
        bf16x8 bp[2][2];
        #pragma unroll
        for (int mt = 0; mt < 2; ++mt) {
            bp[mt][0] = *(const bf16x8*)&Pw[(mt * 16 + l15) * 72 + quad * 8];
            bp[mt][1] = *(const bf16x8*)&Pw[(mt * 16 + l15) * 72 + 32 + quad * 8];
        }
        #pragma unroll
        for (int dt = 0; dt < 4; ++dt) {
            const bf16* hp = hfrag + kc * 4096 + dt * 512;
            bf16x8 aH0 = *(const bf16x8*)hp;
            bf16x8 aH1 = *(const bf16x8*)(hp + 2048);
            #pragma unroll
            for (int mt = 0; mt < 2; ++mt) {
                oacc[mt][dt] = __builtin_amdgcn_mfma_f32_16x16x32_bf16(aH0, bp[mt][0], oacc[mt][dt], 0, 0, 0);
                oacc[mt][dt] = __builtin_amdgcn_mfma_f32_16x16x32_bf16(aH1, bp[mt][1], oacc[mt][dt], 0, 0, 0);
            }
        }
    }

    // ---- epilogue: reduce l over quads, normalize, store bf16 mixed ----
    float inv[2];
    #pragma unroll
    for (int mt = 0; mt < 2; ++mt) {
        float v = lsum[mt];
        v += __shfl_xor(v, 16);
        v += __shfl_xor(v, 32);
        inv[mt] = 1.0f / v;
    }
    #pragma unroll
    for (int mt = 0; mt < 2; ++mt) {
        int pos = q0 + w * 32 + mt * 16 + l15;
        bf16* mb = mixedb + ((size_t)b * 1024 + pos) * 512 + h * 64;
        #pragma unroll
        for (int dt = 0; dt < 4; ++dt) {
            ushort4 pk;
            pk.x = f2bf_bits(oacc[mt][dt][0] * inv[mt]);
            pk.y = f2bf_bits(oacc[mt][dt][1] * inv[mt]);
            pk.z = f2bf_bits(oacc[mt][dt][2] * inv[mt]);
            pk.w = f2bf_bits(oacc[mt][dt][3] * inv[mt]);
            *(ushort4*)(mb + dt * 16 + quad * 4) = pk;
        }
    }
}

// =====================================================================
// Kernel 4: output projection via MFMA (bf16 inputs, fp32 out).
// =====================================================================
__global__ __launch_bounds__(256)
void out_proj_kernel(const bf16* __restrict__ mixedb,
                     const float* __restrict__ Wv, const float* __restrict__ bv,
                     float* __restrict__ out)
{
    __shared__ __attribute__((aligned(16))) bf16 Wvs[64][264];

    const int t  = threadIdx.x;
    const int p0 = blockIdx.x * 64;
    const int w = t >> 6, ln = t & 63, l15 = ln & 15, quad = ln >> 4;

    f32x4 acc[4];
    #pragma unroll
    for (int nt = 0; nt < 4; ++nt) {
        float bvv = bv[nt * 16 + l15];
        acc[nt] = (f32x4){bvv, bvv, bvv, bvv};
    }

    const bf16* arow = mixedb + (size_t)(p0 + w * 16 + l15) * 512;

    for (int half = 0; half < 2; ++half) {
        __syncthreads();
        {
            int c = t >> 2, seg = (t & 3) * 64;
            const float4* src = (const float4*)(Wv + (size_t)c * 512 + half * 256 + seg);
            #pragma unroll
            for (int u = 0; u < 16; ++u) {
                float4 v = src[u];
                bf16x4 pk = {(bf16)v.x, (bf16)v.y, (bf16)v.z, (bf16)v.w};
                *(bf16x4*)&Wvs[c][seg + u * 4] = pk;
            }
        }
        __syncthreads();

        #pragma unroll
        for (int kc = 0; kc < 8; ++kc) {
            bf16x8 a = *(const bf16x8*)(arow + half * 256 + kc * 32 + quad * 8);
            #pragma unroll
            for (int nt = 0; nt < 4; ++nt) {
                bf16x8 bfrag = *(const bf16x8*)&Wvs[nt * 16 + l15][kc * 32 + quad * 8];
                acc[nt] = __builtin_amdgcn_mfma_f32_16x16x32_bf16(a, bfrag, acc[nt], 0, 0, 0);
            }
        }
    }

    #pragma unroll
    for (int nt = 0; nt < 4; ++nt)
        #pragma unroll
        for (int r = 0; r < 4; ++r)
            out[(size_t)(p0 + w * 16 + quad * 4 + r) * 64 + nt * 16 + l15] = acc[nt][r];
}

// =====================================================================
extern "C" void kernel_launch(void* const* d_in, const int* in_sizes, int n_in,
                              void* d_out, int out_size, void* d_ws, size_t ws_size,
                              hipStream_t stream)
{
    const float* hid     = (const float*)d_in[0];
    const float* row_emb = (const float*)d_in[1];
    const float* col_emb = (const float*)d_in[2];
    const float* Wq      = (const float*)d_in[3];
    const float* bq      = (const float*)d_in[4];
    const float* Wk      = (const float*)d_in[5];
    const float* bk      = (const float*)d_in[6];
    const float* Wv      = (const float*)d_in[7];
    const float* bv      = (const float*)d_in[8];
    float* out = (float*)d_out;

    // ws: qb 8MB | kb 8MB | htp 1MB | rowbias 4MB | colbias 4MB | mixedb 8MB
    bf16* qb  = (bf16*)d_ws;
    bf16* kb  = qb + (size_t)64 * 1024 * 64;
    bf16* htp = kb + (size_t)64 * 1024 * 64;
    bf16* rowbias = htp + (size_t)8 * 64 * 1024;
    bf16* colbias = rowbias + (size_t)64 * 1024 * 32;
    bf16* mixedb  = colbias + (size_t)64 * 1024 * 32;

    qkproj_kernel<<<dim3(64, 4, 2), 256, 0, stream>>>(hid, Wq, bq, Wk, bk, qb, kb, htp);
    bias_kernel<<<dim3(64, 4), 256, 0, stream>>>(qb, row_emb, col_emb, rowbias, colbias);
    attn_kernel<<<dim3(8, 64), 256, 0, stream>>>(qb, kb, htp, rowbias, colbias, mixedb);
    out_proj_kernel<<<128, 256, 0, stream>>>(mixedb, Wv, bv, out);
}